// Round 2
// baseline (576.963 us; speedup 1.0000x reference)
//
#include <hip/hip_runtime.h>
#include <cstdint>

// FCOS detection post-process for MI355X.
// Pipeline: score/box decode -> per-image exact top-1000 (bitonic chunk sort +
// tree merge) -> suppression bitmask -> span-based greedy NMS scan -> outputs.

typedef unsigned long long ull;

#define BATCH 16
#define NLOC 17064      // total FPN locations per image
#define NPAD 18432      // padded to 9 * 2048
#define NCHUNK 9
#define CHUNK 2048
#define TOPK 1000
#define TOPKP 1024
#define NCLS 80
#define SCORE_THR 0.05f
#define IOU_THR 0.6f

struct Ptrs { const float* cls[5]; const float* reg[5]; const float* ctr[5]; };

// ---------------------------------------------------------------- kernel 1 --
// One thread per (image, location): argmax over 80 class logits (sigmoid is
// monotonic), score = sqrt(sig(cls_max)*sig(ctr)), box decode, pack sort key.
// Key = (score_bits << 32) | (0xFFFFFFFF - n): descending sort == lax.top_k
// order (ties -> smaller index first). Padding locations get key 0.
__global__ __launch_bounds__(256) void score_kernel(Ptrs p, ull* __restrict__ keys,
                                                    int* __restrict__ labels,
                                                    float* __restrict__ boxes) {
  int idx = blockIdx.x * 256 + threadIdx.x;
  if (idx >= BATCH * NPAD) return;
  int b = idx / NPAD, n = idx - b * NPAD;
  if (n >= NLOC) { keys[idx] = 0ull; return; }

  int lvl, off, lw, st, H;
  if (n < 12800)      { lvl=0; off=0;     lw=7; st=8;   H=100; }
  else if (n < 16000) { lvl=1; off=12800; lw=6; st=16;  H=50;  }
  else if (n < 16800) { lvl=2; off=16000; lw=5; st=32;  H=25;  }
  else if (n < 17008) { lvl=3; off=16800; lw=4; st=64;  H=13;  }
  else                { lvl=4; off=17008; lw=3; st=128; H=7;   }
  int hw = n - off;
  int w = hw & ((1 << lw) - 1), h = hw >> lw;
  int HW = H << lw;
  float fs = (float)st, half = fs * 0.5f;
  float x = (float)w * fs + half, y = (float)h * fs + half;

  // coalesced across threads (consecutive hw) for each class c
  const float* cb = p.cls[lvl] + (size_t)b * NCLS * HW + hw;
  float best = cb[0]; int bi = 0;
  for (int c = 1; c < NCLS; ++c) {
    float v = cb[(size_t)c * HW];
    if (v > best) { best = v; bi = c; }   // strict > keeps first max (jnp.argmax)
  }
  const float* rb = p.reg[lvl] + (size_t)b * 4 * HW + hw;
  float r0 = rb[0], r1 = rb[HW], r2 = rb[2 * (size_t)HW], r3 = rb[3 * (size_t)HW];
  float ct = p.ctr[lvl][(size_t)b * HW + hw];

  float pcls = 1.f / (1.f + expf(-best));
  float pctr = 1.f / (1.f + expf(-ct));
  float score = sqrtf(pcls * pctr);   // (0,1), always positive -> monotonic bits

  keys[idx] = ((ull)__float_as_uint(score) << 32) | (ull)(0xFFFFFFFFu - (unsigned)n);
  labels[(size_t)b * NLOC + n] = bi + 1;
  float* bx = boxes + ((size_t)b * NLOC + n) * 4;
  bx[0] = x - r0; bx[1] = y - r1; bx[2] = x + r2; bx[3] = y + r3;
}

// ---------------------------------------------------------------- kernel 2 --
// Bitonic sort of one 2048 chunk in LDS (descending); emit top-1024.
__global__ __launch_bounds__(512) void chunk_sort_kernel(const ull* __restrict__ keys,
                                                         ull* __restrict__ runs) {
  __shared__ ull s[CHUNK];
  int b = blockIdx.x / NCHUNK, c = blockIdx.x % NCHUNK;
  const ull* src = keys + (size_t)b * NPAD + (size_t)c * CHUNK;
  for (int i = threadIdx.x; i < CHUNK; i += 512) s[i] = src[i];
  __syncthreads();
  for (int k = 2; k <= CHUNK; k <<= 1) {
    for (int j = k >> 1; j > 0; j >>= 1) {
      for (int t = threadIdx.x; t < CHUNK / 2; t += 512) {
        int i = ((t & ~(j - 1)) << 1) | (t & (j - 1));
        int ixj = i | j;
        bool desc = (i & k) == 0;
        ull a = s[i], bb = s[ixj];
        bool sw = desc ? (a < bb) : (a > bb);
        if (sw) { s[i] = bb; s[ixj] = a; }
      }
      __syncthreads();
    }
  }
  ull* dst = runs + ((size_t)b * NCHUNK + c) * TOPKP;
  for (int i = threadIdx.x; i < TOPKP; i += 512) dst[i] = s[i];
}

// ---------------------------------------------------------------- kernel 3 --
// One tree-merge level: block (b,p) merges src runs (2p,2p+1) -> dst run p,
// keeping only the top-1024 (first bitonic-merge pass + descending clean of
// the top half). Carry block copies the odd run through. Ping-pong buffers.
__global__ __launch_bounds__(512) void merge_level_kernel(const ull* __restrict__ src,
    ull* __restrict__ dst, int npairs, int carry, int srcRPI, int dstRPI) {
  int per = npairs + carry;
  int b = blockIdx.x / per, p = blockIdx.x % per;
  const ull* sb = src + (size_t)b * srcRPI * TOPKP;
  ull* db = dst + (size_t)b * dstRPI * TOPKP;
  int tid = threadIdx.x;
  if (p >= npairs) {   // carry: copy last odd run through
    for (int i = tid; i < TOPKP; i += 512)
      db[(size_t)p * TOPKP + i] = sb[(size_t)(2 * npairs) * TOPKP + i];
    return;
  }
  __shared__ ull m[TOPKP];
  const ull* A = sb + (size_t)(2 * p) * TOPKP;
  const ull* B = sb + (size_t)(2 * p + 1) * TOPKP;
  // pass j=1024 of the 2048 bitonic merge: top half = max(A[i], B[1023-i])
  for (int i = tid; i < TOPKP; i += 512) {
    ull a = A[i], c = B[TOPKP - 1 - i];
    m[i] = a > c ? a : c;
  }
  __syncthreads();
  // descending bitonic clean of the (bitonic) top half
  for (int j = TOPKP / 2; j > 0; j >>= 1) {
    for (int t = tid; t < TOPKP / 2; t += 512) {
      int i = ((t & ~(j - 1)) << 1) | (t & (j - 1));
      int ixj = i | j;
      ull a = m[i], c = m[ixj];
      if (a < c) { m[i] = c; m[ixj] = a; }
    }
    __syncthreads();
  }
  for (int i = tid; i < TOPKP; i += 512) db[(size_t)p * TOPKP + i] = m[i];
}

// ---------------------------------------------------------------- kernel 4 --
// Decode keys, gather label/box, write output boxes, coord_max reduction
// (exact: max is order-independent), class-offset boxes, valid-bit words.
__global__ __launch_bounds__(256) void gather_kernel(const ull* __restrict__ topkeys,
    const int* __restrict__ labels, const float* __restrict__ boxes,
    float* __restrict__ topS, int* __restrict__ topL, float* __restrict__ topOB,
    ull* __restrict__ validWords, float* __restrict__ outBoxes) {
  __shared__ float red[256];
  __shared__ float s_cmax;
  int b = blockIdx.x, tid = threadIdx.x;
  float lmax = 0.f;   // reference maxes over where(valid, bx, 0) -> zeros included
  for (int k = tid; k < TOPKP; k += 256) {
    ull key = topkeys[(size_t)b * TOPKP + k];
    float sc = 0.f; int lb = 0;
    float b0 = 0.f, b1 = 0.f, b2 = 0.f, b3 = 0.f;
    bool inR = (k < TOPK);
    if (inR) {
      sc = __uint_as_float((unsigned)(key >> 32));
      unsigned n = 0xFFFFFFFFu - (unsigned)(key & 0xFFFFFFFFull);
      lb = labels[(size_t)b * NLOC + n];
      const float* bp = boxes + ((size_t)b * NLOC + n) * 4;
      b0 = bp[0]; b1 = bp[1]; b2 = bp[2]; b3 = bp[3];
      float* ob = outBoxes + ((size_t)b * TOPK + k) * 4;
      ob[0] = b0; ob[1] = b1; ob[2] = b2; ob[3] = b3;   // boxes output: all 1000
    }
    topS[(size_t)b * TOPKP + k] = sc;
    topL[(size_t)b * TOPKP + k] = lb;
    float* tb = topOB + ((size_t)b * TOPKP + k) * 4;
    tb[0] = b0; tb[1] = b1; tb[2] = b2; tb[3] = b3;
    bool valid = inR && (sc > SCORE_THR);
    if (valid) lmax = fmaxf(lmax, fmaxf(fmaxf(b0, b1), fmaxf(b2, b3)));
    ull vb = __ballot(valid ? 1 : 0);
    if ((tid & 63) == 0) validWords[b * 16 + (k >> 6)] = vb;
  }
  red[tid] = lmax;
  __syncthreads();
  for (int sft = 128; sft > 0; sft >>= 1) {
    if (tid < sft) red[tid] = fmaxf(red[tid], red[tid + sft]);
    __syncthreads();
  }
  if (tid == 0) s_cmax = red[0];
  __syncthreads();
  float offb = s_cmax + 1.0f;
  for (int k = tid; k < TOPKP; k += 256) {
    float off = (float)topL[(size_t)b * TOPKP + k] * offb;   // class-offset trick
    float* tb = topOB + ((size_t)b * TOPKP + k) * 4;
    tb[0] += off; tb[1] += off; tb[2] += off; tb[3] += off;
  }
}

// ---------------------------------------------------------------- kernel 5 --
// Suppression bitmask: block (b,i), thread j: bit = (j>i) & (iou(i,j) > thr).
// 16 uint64 words per row via per-wave ballot. Row stride = 16 words; rows
// stored at (b*TOPKP + i). FP op order mirrors reference.
__global__ __launch_bounds__(1024) void sup_kernel(const float* __restrict__ topOB,
                                                   ull* __restrict__ sup) {
  int bid = blockIdx.x;
  int b = bid / TOPK, i = bid - b * TOPK;
  int j = threadIdx.x;
  const float4* OB = (const float4*)topOB + (size_t)b * TOPKP;
  float4 A = OB[i];
  float aw = fmaxf(A.z - A.x, 0.f), ah = fmaxf(A.w - A.y, 0.f);
  float areaA = aw * ah;
  bool bit = false;
  if (j > i && j < TOPK) {
    float4 Bx = OB[j];
    float bw = fmaxf(Bx.z - Bx.x, 0.f), bh = fmaxf(Bx.w - Bx.y, 0.f);
    float areaB = bw * bh;
    float ix1 = fmaxf(A.x, Bx.x), iy1 = fmaxf(A.y, Bx.y);
    float ix2 = fminf(A.z, Bx.z), iy2 = fminf(A.w, Bx.w);
    float inter = fmaxf(ix2 - ix1, 0.f) * fmaxf(iy2 - iy1, 0.f);
    float uni = areaA + areaB - inter;
    float iou = inter / fmaxf(uni, 1e-9f);
    bit = iou > IOU_THR;
  }
  ull m = __ballot(bit ? 1 : 0);
  if ((j & 63) == 0) sup[((size_t)b * TOPKP + i) * 16 + (j >> 6)] = m;
}

// ---------------------------------------------------------------- kernel 6 --
// Span-based greedy scan, 1 wave per image. Lanes 0..15 own removed word lane.
// Per 64-candidate span w: only removed word w is ever TESTED, and row i's
// word-w part is a single value (diag) -> all 64 lanes redundantly run the
// 64-step serial scan on a broadcast copy of word w using broadcast-address
// diag loads (pure-VALU chain, no shfl). Then lanes 0..15 OR the kept rows
// into their own word (coalesced loads). 1 shfl per span instead of 1000.
__global__ __launch_bounds__(64) void nms_scan_kernel(const ull* __restrict__ sup,
    const ull* __restrict__ validWords, const float* __restrict__ topS,
    const int* __restrict__ topL, float* __restrict__ out) {
  int b = blockIdx.x, lane = threadIdx.x;
  const ull* S = sup + (size_t)b * TOPKP * 16;
  ull rm = 0xFFFFFFFFFFFFFFFFull;
  if (lane < 16) rm = ~validWords[b * 16 + lane];   // removed = ~valid initially

  for (int w = 0; w < 16; ++w) {
    ull rmw = __shfl(rm, w);            // current removed word w (1 shfl/span)
    const ull* D = S + (size_t)w * 64 * 16 + w;     // diag: row (w*64+k) word w
    ull d[64];
#pragma unroll
    for (int k = 0; k < 64; ++k) d[k] = D[(size_t)k * 16];   // broadcast loads
    ull km = 0;                          // kept mask for this span
#pragma unroll
    for (int k = 0; k < 64; ++k) {
      if (!((rmw >> k) & 1ull)) { rmw |= d[k]; km |= (1ull << k); }
    }
    if (lane < 16) {
#pragma unroll
      for (int k = 0; k < 64; ++k) {
        ull row = S[((size_t)w * 64 + k) * 16 + lane];   // coalesced 128B
        if ((km >> k) & 1ull) rm |= row;
      }
    }
  }

  ull keep_na = ~rm;   // lanes 0..15: keep word lane (~rm subset of valid)
  const float* tS = topS + (size_t)b * TOPKP;
  const int*   tL = topL + (size_t)b * TOPKP;
  float* outS = out;                          // [16,1000]
  float* outL = out + BATCH * TOPK;           // [16,1000] labels as float
  float* outK = out + BATCH * TOPK * 6;       // after boxes block
  for (int t = 0; t < 16; ++t) {
    int j = t * 64 + lane;
    ull kw = __shfl(keep_na, t);
    if (j < TOPK) {
      bool kp = (kw >> lane) & 1ull;
      outS[(size_t)b * TOPK + j] = kp ? tS[j] : 0.f;
      outL[(size_t)b * TOPK + j] = kp ? (float)tL[j] : 0.f;
      outK[(size_t)b * TOPK + j] = kp ? 1.f : 0.f;
    }
  }
}

// -------------------------------------------------------------------- host --
extern "C" void kernel_launch(void* const* d_in, const int* in_sizes, int n_in,
                              void* d_out, int out_size, void* d_ws, size_t ws_size,
                              hipStream_t stream) {
  Ptrs p;
  for (int l = 0; l < 5; ++l) {
    p.cls[l] = (const float*)d_in[l];
    p.reg[l] = (const float*)d_in[5 + l];
    p.ctr[l] = (const float*)d_in[10 + l];
  }
  char* ws = (char*)d_ws;
  size_t o = 0;
  auto alloc = [&](size_t bytes) -> void* {
    void* r = ws + o; o += (bytes + 255) & ~(size_t)255; return r;
  };
  ull*   keys       = (ull*)  alloc((size_t)BATCH * NPAD * 8);
  int*   labels     = (int*)  alloc((size_t)BATCH * NLOC * 4);
  float* boxes      = (float*)alloc((size_t)BATCH * NLOC * 16);
  ull*   runs       = (ull*)  alloc((size_t)BATCH * NCHUNK * TOPKP * 8);
  ull*   runs2      = (ull*)  alloc((size_t)BATCH * NCHUNK * TOPKP * 8);
  ull*   topkeys    = (ull*)  alloc((size_t)BATCH * TOPKP * 8);
  float* topS       = (float*)alloc((size_t)BATCH * TOPKP * 4);
  int*   topL       = (int*)  alloc((size_t)BATCH * TOPKP * 4);
  float* topOB      = (float*)alloc((size_t)BATCH * TOPKP * 16);
  ull*   validWords = (ull*)  alloc((size_t)BATCH * 16 * 8);
  ull*   sup        = (ull*)  alloc((size_t)BATCH * TOPKP * 16 * 8);

  float* out = (float*)d_out;
  float* outBoxes = out + 2 * BATCH * TOPK;   // offset 32000

  hipLaunchKernelGGL(score_kernel, dim3((BATCH * NPAD + 255) / 256), dim3(256), 0, stream,
                     p, keys, labels, boxes);
  hipLaunchKernelGGL(chunk_sort_kernel, dim3(BATCH * NCHUNK), dim3(512), 0, stream,
                     keys, runs);
  // tree merge: 9 -> 5 -> 3 -> 2 -> 1 (ping-pong runs/runs2)
  hipLaunchKernelGGL(merge_level_kernel, dim3(BATCH * 5), dim3(512), 0, stream,
                     runs, runs2, 4, 1, NCHUNK, NCHUNK);
  hipLaunchKernelGGL(merge_level_kernel, dim3(BATCH * 3), dim3(512), 0, stream,
                     runs2, runs, 2, 1, NCHUNK, NCHUNK);
  hipLaunchKernelGGL(merge_level_kernel, dim3(BATCH * 2), dim3(512), 0, stream,
                     runs, runs2, 1, 1, NCHUNK, NCHUNK);
  hipLaunchKernelGGL(merge_level_kernel, dim3(BATCH * 1), dim3(512), 0, stream,
                     runs2, topkeys, 1, 0, NCHUNK, 1);
  hipLaunchKernelGGL(gather_kernel, dim3(BATCH), dim3(256), 0, stream,
                     topkeys, labels, boxes, topS, topL, topOB, validWords, outBoxes);
  hipLaunchKernelGGL(sup_kernel, dim3(BATCH * TOPK), dim3(1024), 0, stream,
                     topOB, sup);
  hipLaunchKernelGGL(nms_scan_kernel, dim3(BATCH), dim3(64), 0, stream,
                     sup, validWords, topS, topL, out);
}

// Round 6
// 547.615 us; speedup vs baseline: 1.0536x; 1.0536x over previous
//
#include <hip/hip_runtime.h>
#include <cstdint>

// FCOS detection post-process for MI355X.
// Pipeline: score/box decode -> per-image exact top-1000 (bitonic chunk sort +
// tree merge) -> suppression bitmask -> span-based greedy NMS scan -> outputs.

typedef unsigned long long ull;

#define BATCH 16
#define NLOC 17064      // total FPN locations per image
#define NPAD 18432      // padded to 9 * 2048
#define NCHUNK 9
#define CHUNK 2048
#define TOPK 1000
#define TOPKP 1024
#define NCLS 80
#define SCORE_THR 0.05f
#define IOU_THR 0.6f

struct Ptrs { const float* cls[5]; const float* reg[5]; const float* ctr[5]; };

// ---------------------------------------------------------------- kernel 1 --
// One thread per (image, location): argmax over 80 class logits (sigmoid is
// monotonic), score = sqrt(sig(cls_max)*sig(ctr)), box decode, pack sort key.
// Key = (score_bits << 32) | (0xFFFFFFFF - n): descending sort == lax.top_k
// order (ties -> smaller index first). Padding locations get key 0.
__global__ __launch_bounds__(256) void score_kernel(Ptrs p, ull* __restrict__ keys,
                                                    int* __restrict__ labels,
                                                    float* __restrict__ boxes) {
  int idx = blockIdx.x * 256 + threadIdx.x;
  if (idx >= BATCH * NPAD) return;
  int b = idx / NPAD, n = idx - b * NPAD;
  if (n >= NLOC) { keys[idx] = 0ull; return; }

  int lvl, off, lw, st, H;
  if (n < 12800)      { lvl=0; off=0;     lw=7; st=8;   H=100; }
  else if (n < 16000) { lvl=1; off=12800; lw=6; st=16;  H=50;  }
  else if (n < 16800) { lvl=2; off=16000; lw=5; st=32;  H=25;  }
  else if (n < 17008) { lvl=3; off=16800; lw=4; st=64;  H=13;  }
  else                { lvl=4; off=17008; lw=3; st=128; H=7;   }
  int hw = n - off;
  int w = hw & ((1 << lw) - 1), h = hw >> lw;
  int HW = H << lw;
  float fs = (float)st, half = fs * 0.5f;
  float x = (float)w * fs + half, y = (float)h * fs + half;

  // coalesced across threads (consecutive hw) for each class c
  const float* cb = p.cls[lvl] + (size_t)b * NCLS * HW + hw;
  float best = cb[0]; int bi = 0;
  for (int c = 1; c < NCLS; ++c) {
    float v = cb[(size_t)c * HW];
    if (v > best) { best = v; bi = c; }   // strict > keeps first max (jnp.argmax)
  }
  const float* rb = p.reg[lvl] + (size_t)b * 4 * HW + hw;
  float r0 = rb[0], r1 = rb[HW], r2 = rb[2 * (size_t)HW], r3 = rb[3 * (size_t)HW];
  float ct = p.ctr[lvl][(size_t)b * HW + hw];

  float pcls = 1.f / (1.f + expf(-best));
  float pctr = 1.f / (1.f + expf(-ct));
  float score = sqrtf(pcls * pctr);   // (0,1), always positive -> monotonic bits

  keys[idx] = ((ull)__float_as_uint(score) << 32) | (ull)(0xFFFFFFFFu - (unsigned)n);
  labels[(size_t)b * NLOC + n] = bi + 1;
  float* bx = boxes + ((size_t)b * NLOC + n) * 4;
  bx[0] = x - r0; bx[1] = y - r1; bx[2] = x + r2; bx[3] = y + r3;
}

// ---------------------------------------------------------------- kernel 2 --
// Bitonic sort of one 2048 chunk in LDS (descending); emit top-1024.
__global__ __launch_bounds__(512) void chunk_sort_kernel(const ull* __restrict__ keys,
                                                         ull* __restrict__ runs) {
  __shared__ ull s[CHUNK];
  int b = blockIdx.x / NCHUNK, c = blockIdx.x % NCHUNK;
  const ull* src = keys + (size_t)b * NPAD + (size_t)c * CHUNK;
  for (int i = threadIdx.x; i < CHUNK; i += 512) s[i] = src[i];
  __syncthreads();
  for (int k = 2; k <= CHUNK; k <<= 1) {
    for (int j = k >> 1; j > 0; j >>= 1) {
      for (int t = threadIdx.x; t < CHUNK / 2; t += 512) {
        int i = ((t & ~(j - 1)) << 1) | (t & (j - 1));
        int ixj = i | j;
        bool desc = (i & k) == 0;
        ull a = s[i], bb = s[ixj];
        bool sw = desc ? (a < bb) : (a > bb);
        if (sw) { s[i] = bb; s[ixj] = a; }
      }
      __syncthreads();
    }
  }
  ull* dst = runs + ((size_t)b * NCHUNK + c) * TOPKP;
  for (int i = threadIdx.x; i < TOPKP; i += 512) dst[i] = s[i];
}

// ---------------------------------------------------------------- kernel 3 --
// One tree-merge level: block (b,p) merges src runs (2p,2p+1) -> dst run p,
// keeping only the top-1024 (first bitonic-merge pass + descending clean of
// the top half). Carry block copies the odd run through. Ping-pong buffers.
__global__ __launch_bounds__(512) void merge_level_kernel(const ull* __restrict__ src,
    ull* __restrict__ dst, int npairs, int carry, int srcRPI, int dstRPI) {
  int per = npairs + carry;
  int b = blockIdx.x / per, p = blockIdx.x % per;
  const ull* sb = src + (size_t)b * srcRPI * TOPKP;
  ull* db = dst + (size_t)b * dstRPI * TOPKP;
  int tid = threadIdx.x;
  if (p >= npairs) {   // carry: copy last odd run through
    for (int i = tid; i < TOPKP; i += 512)
      db[(size_t)p * TOPKP + i] = sb[(size_t)(2 * npairs) * TOPKP + i];
    return;
  }
  __shared__ ull m[TOPKP];
  const ull* A = sb + (size_t)(2 * p) * TOPKP;
  const ull* B = sb + (size_t)(2 * p + 1) * TOPKP;
  // pass j=1024 of the 2048 bitonic merge: top half = max(A[i], B[1023-i])
  for (int i = tid; i < TOPKP; i += 512) {
    ull a = A[i], c = B[TOPKP - 1 - i];
    m[i] = a > c ? a : c;
  }
  __syncthreads();
  // descending bitonic clean of the (bitonic) top half
  for (int j = TOPKP / 2; j > 0; j >>= 1) {
    for (int t = tid; t < TOPKP / 2; t += 512) {
      int i = ((t & ~(j - 1)) << 1) | (t & (j - 1));
      int ixj = i | j;
      ull a = m[i], c = m[ixj];
      if (a < c) { m[i] = c; m[ixj] = a; }
    }
    __syncthreads();
  }
  for (int i = tid; i < TOPKP; i += 512) db[(size_t)p * TOPKP + i] = m[i];
}

// ---------------------------------------------------------------- kernel 4 --
// Decode keys, gather label/box, write output boxes, coord_max reduction
// (exact: max is order-independent), class-offset boxes, valid-bit words.
__global__ __launch_bounds__(256) void gather_kernel(const ull* __restrict__ topkeys,
    const int* __restrict__ labels, const float* __restrict__ boxes,
    float* __restrict__ topS, int* __restrict__ topL, float* __restrict__ topOB,
    ull* __restrict__ validWords, float* __restrict__ outBoxes) {
  __shared__ float red[256];
  __shared__ float s_cmax;
  int b = blockIdx.x, tid = threadIdx.x;
  float lmax = 0.f;   // reference maxes over where(valid, bx, 0) -> zeros included
  for (int k = tid; k < TOPKP; k += 256) {
    ull key = topkeys[(size_t)b * TOPKP + k];
    float sc = 0.f; int lb = 0;
    float b0 = 0.f, b1 = 0.f, b2 = 0.f, b3 = 0.f;
    bool inR = (k < TOPK);
    if (inR) {
      sc = __uint_as_float((unsigned)(key >> 32));
      unsigned n = 0xFFFFFFFFu - (unsigned)(key & 0xFFFFFFFFull);
      lb = labels[(size_t)b * NLOC + n];
      const float* bp = boxes + ((size_t)b * NLOC + n) * 4;
      b0 = bp[0]; b1 = bp[1]; b2 = bp[2]; b3 = bp[3];
      float* ob = outBoxes + ((size_t)b * TOPK + k) * 4;
      ob[0] = b0; ob[1] = b1; ob[2] = b2; ob[3] = b3;   // boxes output: all 1000
    }
    topS[(size_t)b * TOPKP + k] = sc;
    topL[(size_t)b * TOPKP + k] = lb;
    float* tb = topOB + ((size_t)b * TOPKP + k) * 4;
    tb[0] = b0; tb[1] = b1; tb[2] = b2; tb[3] = b3;
    bool valid = inR && (sc > SCORE_THR);
    if (valid) lmax = fmaxf(lmax, fmaxf(fmaxf(b0, b1), fmaxf(b2, b3)));
    ull vb = __ballot(valid ? 1 : 0);
    if ((tid & 63) == 0) validWords[b * 16 + (k >> 6)] = vb;
  }
  red[tid] = lmax;
  __syncthreads();
  for (int sft = 128; sft > 0; sft >>= 1) {
    if (tid < sft) red[tid] = fmaxf(red[tid], red[tid + sft]);
    __syncthreads();
  }
  if (tid == 0) s_cmax = red[0];
  __syncthreads();
  float offb = s_cmax + 1.0f;
  for (int k = tid; k < TOPKP; k += 256) {
    float off = (float)topL[(size_t)b * TOPKP + k] * offb;   // class-offset trick
    float* tb = topOB + ((size_t)b * TOPKP + k) * 4;
    tb[0] += off; tb[1] += off; tb[2] += off; tb[3] += off;
  }
}

// ---------------------------------------------------------------- kernel 5 --
// Suppression bitmask: block (b,i), thread j: bit = (j>i) & (iou(i,j) > thr).
// 16 uint64 words per row via per-wave ballot. Row stride = 16 words; rows
// stored at (b*TOPKP + i). FP op order mirrors reference.
__global__ __launch_bounds__(1024) void sup_kernel(const float* __restrict__ topOB,
                                                   ull* __restrict__ sup) {
  int bid = blockIdx.x;
  int b = bid / TOPK, i = bid - b * TOPK;
  int j = threadIdx.x;
  const float4* OB = (const float4*)topOB + (size_t)b * TOPKP;
  float4 A = OB[i];
  float aw = fmaxf(A.z - A.x, 0.f), ah = fmaxf(A.w - A.y, 0.f);
  float areaA = aw * ah;
  bool bit = false;
  if (j > i && j < TOPK) {
    float4 Bx = OB[j];
    float bw = fmaxf(Bx.z - Bx.x, 0.f), bh = fmaxf(Bx.w - Bx.y, 0.f);
    float areaB = bw * bh;
    float ix1 = fmaxf(A.x, Bx.x), iy1 = fmaxf(A.y, Bx.y);
    float ix2 = fminf(A.z, Bx.z), iy2 = fminf(A.w, Bx.w);
    float inter = fmaxf(ix2 - ix1, 0.f) * fmaxf(iy2 - iy1, 0.f);
    float uni = areaA + areaB - inter;
    float iou = inter / fmaxf(uni, 1e-9f);
    bit = iou > IOU_THR;
  }
  ull m = __ballot(bit ? 1 : 0);
  if ((j & 63) == 0) sup[((size_t)b * TOPKP + i) * 16 + (j >> 6)] = m;
}

// ---------------------------------------------------------------- kernel 6 --
// Span-based greedy scan, 1 wave per image. Lanes 0..15 own removed word lane.
// Per 64-candidate span w: only removed word w is ever TESTED, and row i's
// word-w part is one value (diag) -> all lanes redundantly run the 64-step
// serial scan on a broadcast copy of word w, with diag values prefetched
// 8-deep into NAMED registers (no arrays -> no scratch; R2's ull d[64]
// spilled to scratch and cost 3x). Then lanes 0..15 stream the kept rows'
// words into their own removed word. 1 shfl per span.
__global__ __launch_bounds__(64) void nms_scan_kernel(const ull* __restrict__ sup,
    const ull* __restrict__ validWords, const float* __restrict__ topS,
    const int* __restrict__ topL, float* __restrict__ out) {
  int b = blockIdx.x, lane = threadIdx.x;
  const ull* S = sup + (size_t)b * TOPKP * 16;
  ull rm = 0xFFFFFFFFFFFFFFFFull;
  if (lane < 16) rm = ~validWords[b * 16 + lane];   // removed = ~valid initially

  for (int w = 0; w < 16; ++w) {
    ull rmw = __shfl(rm, w);            // current removed word w (1 shfl/span)
    const ull* D = S + (size_t)w * 64 * 16 + w;     // diag: row (w*64+k) word w
    // rolling 8-deep prefetch of diag values in named regs
    ull d0 = D[0 * 16], d1 = D[1 * 16], d2 = D[2 * 16], d3 = D[3 * 16];
    ull d4 = D[4 * 16], d5 = D[5 * 16], d6 = D[6 * 16], d7 = D[7 * 16];
    ull km = 0;                          // kept mask for this span
    for (int g = 0; g < 64; g += 8) {
#define STEPA(u) { ull dv = d##u; int nk = g + 8 + u;                          \
      d##u = (nk < 64) ? D[(size_t)nk * 16] : 0ull;                            \
      if (!((rmw >> (g + u)) & 1ull)) { rmw |= dv; km |= (1ull << (g + u)); } }
      STEPA(0) STEPA(1) STEPA(2) STEPA(3) STEPA(4) STEPA(5) STEPA(6) STEPA(7)
#undef STEPA
    }
    if (lane < 16) {
      const ull* R = S + (size_t)w * 64 * 16 + lane;
#pragma unroll 8
      for (int k = 0; k < 64; ++k) {
        ull row = R[(size_t)k * 16];     // coalesced 128B across lanes 0..15
        if ((km >> k) & 1ull) rm |= row;
      }
    }
  }

  ull keep_na = ~rm;   // lanes 0..15: keep word lane (~rm subset of valid)
  const float* tS = topS + (size_t)b * TOPKP;
  const int*   tL = topL + (size_t)b * TOPKP;
  float* outS = out;                          // [16,1000]
  float* outL = out + BATCH * TOPK;           // [16,1000] labels as float
  float* outK = out + BATCH * TOPK * 6;       // after boxes block
  for (int t = 0; t < 16; ++t) {
    int j = t * 64 + lane;
    ull kw = __shfl(keep_na, t);
    if (j < TOPK) {
      bool kp = (kw >> lane) & 1ull;
      outS[(size_t)b * TOPK + j] = kp ? tS[j] : 0.f;
      outL[(size_t)b * TOPK + j] = kp ? (float)tL[j] : 0.f;
      outK[(size_t)b * TOPK + j] = kp ? 1.f : 0.f;
    }
  }
}

// -------------------------------------------------------------------- host --
extern "C" void kernel_launch(void* const* d_in, const int* in_sizes, int n_in,
                              void* d_out, int out_size, void* d_ws, size_t ws_size,
                              hipStream_t stream) {
  Ptrs p;
  for (int l = 0; l < 5; ++l) {
    p.cls[l] = (const float*)d_in[l];
    p.reg[l] = (const float*)d_in[5 + l];
    p.ctr[l] = (const float*)d_in[10 + l];
  }
  char* ws = (char*)d_ws;
  size_t o = 0;
  auto alloc = [&](size_t bytes) -> void* {
    void* r = ws + o; o += (bytes + 255) & ~(size_t)255; return r;
  };
  ull*   keys       = (ull*)  alloc((size_t)BATCH * NPAD * 8);
  int*   labels     = (int*)  alloc((size_t)BATCH * NLOC * 4);
  float* boxes      = (float*)alloc((size_t)BATCH * NLOC * 16);
  ull*   runs       = (ull*)  alloc((size_t)BATCH * NCHUNK * TOPKP * 8);
  ull*   runs2      = (ull*)  alloc((size_t)BATCH * NCHUNK * TOPKP * 8);
  ull*   topkeys    = (ull*)  alloc((size_t)BATCH * TOPKP * 8);
  float* topS       = (float*)alloc((size_t)BATCH * TOPKP * 4);
  int*   topL       = (int*)  alloc((size_t)BATCH * TOPKP * 4);
  float* topOB      = (float*)alloc((size_t)BATCH * TOPKP * 16);
  ull*   validWords = (ull*)  alloc((size_t)BATCH * 16 * 8);
  ull*   sup        = (ull*)  alloc((size_t)BATCH * TOPKP * 16 * 8);

  float* out = (float*)d_out;
  float* outBoxes = out + 2 * BATCH * TOPK;   // offset 32000

  hipLaunchKernelGGL(score_kernel, dim3((BATCH * NPAD + 255) / 256), dim3(256), 0, stream,
                     p, keys, labels, boxes);
  hipLaunchKernelGGL(chunk_sort_kernel, dim3(BATCH * NCHUNK), dim3(512), 0, stream,
                     keys, runs);
  // tree merge: 9 -> 5 -> 3 -> 2 -> 1 (ping-pong runs/runs2)
  hipLaunchKernelGGL(merge_level_kernel, dim3(BATCH * 5), dim3(512), 0, stream,
                     runs, runs2, 4, 1, NCHUNK, NCHUNK);
  hipLaunchKernelGGL(merge_level_kernel, dim3(BATCH * 3), dim3(512), 0, stream,
                     runs2, runs, 2, 1, NCHUNK, NCHUNK);
  hipLaunchKernelGGL(merge_level_kernel, dim3(BATCH * 2), dim3(512), 0, stream,
                     runs, runs2, 1, 1, NCHUNK, NCHUNK);
  hipLaunchKernelGGL(merge_level_kernel, dim3(BATCH * 1), dim3(512), 0, stream,
                     runs2, topkeys, 1, 0, NCHUNK, 1);
  hipLaunchKernelGGL(gather_kernel, dim3(BATCH), dim3(256), 0, stream,
                     topkeys, labels, boxes, topS, topL, topOB, validWords, outBoxes);
  hipLaunchKernelGGL(sup_kernel, dim3(BATCH * TOPK), dim3(1024), 0, stream,
                     topOB, sup);
  hipLaunchKernelGGL(nms_scan_kernel, dim3(BATCH), dim3(64), 0, stream,
                     sup, validWords, topS, topL, out);
}

// Round 7
// 255.592 us; speedup vs baseline: 2.2574x; 2.1425x over previous
//
#include <hip/hip_runtime.h>
#include <cstdint>

// FCOS detection post-process for MI355X.
// Pipeline: score/box decode -> per-image exact top-1000 (bitonic chunk sort +
// tree merge) -> suppression bitmask -> span-based greedy NMS scan -> outputs.

typedef unsigned long long ull;

#define BATCH 16
#define NLOC 17064      // total FPN locations per image
#define NPAD 18432      // padded to 9 * 2048
#define NCHUNK 9
#define CHUNK 2048
#define TOPK 1000
#define TOPKP 1024
#define NCLS 80
#define SCORE_THR 0.05f
#define IOU_THR 0.6f

struct Ptrs { const float* cls[5]; const float* reg[5]; const float* ctr[5]; };

// ---------------------------------------------------------------- kernel 1 --
// One thread per (image, location): argmax over 80 class logits (sigmoid is
// monotonic), score = sqrt(sig(cls_max)*sig(ctr)), box decode, pack sort key.
// Key = (score_bits << 32) | (0xFFFFFFFF - n): descending sort == lax.top_k
// order (ties -> smaller index first). Padding locations get key 0.
__global__ __launch_bounds__(256) void score_kernel(Ptrs p, ull* __restrict__ keys,
                                                    int* __restrict__ labels,
                                                    float* __restrict__ boxes) {
  int idx = blockIdx.x * 256 + threadIdx.x;
  if (idx >= BATCH * NPAD) return;
  int b = idx / NPAD, n = idx - b * NPAD;
  if (n >= NLOC) { keys[idx] = 0ull; return; }

  int lvl, off, lw, st, H;
  if (n < 12800)      { lvl=0; off=0;     lw=7; st=8;   H=100; }
  else if (n < 16000) { lvl=1; off=12800; lw=6; st=16;  H=50;  }
  else if (n < 16800) { lvl=2; off=16000; lw=5; st=32;  H=25;  }
  else if (n < 17008) { lvl=3; off=16800; lw=4; st=64;  H=13;  }
  else                { lvl=4; off=17008; lw=3; st=128; H=7;   }
  int hw = n - off;
  int w = hw & ((1 << lw) - 1), h = hw >> lw;
  int HW = H << lw;
  float fs = (float)st, half = fs * 0.5f;
  float x = (float)w * fs + half, y = (float)h * fs + half;

  // coalesced across threads (consecutive hw) for each class c
  const float* cb = p.cls[lvl] + (size_t)b * NCLS * HW + hw;
  float best = cb[0]; int bi = 0;
  for (int c = 1; c < NCLS; ++c) {
    float v = cb[(size_t)c * HW];
    if (v > best) { best = v; bi = c; }   // strict > keeps first max (jnp.argmax)
  }
  const float* rb = p.reg[lvl] + (size_t)b * 4 * HW + hw;
  float r0 = rb[0], r1 = rb[HW], r2 = rb[2 * (size_t)HW], r3 = rb[3 * (size_t)HW];
  float ct = p.ctr[lvl][(size_t)b * HW + hw];

  float pcls = 1.f / (1.f + expf(-best));
  float pctr = 1.f / (1.f + expf(-ct));
  float score = sqrtf(pcls * pctr);   // (0,1), always positive -> monotonic bits

  keys[idx] = ((ull)__float_as_uint(score) << 32) | (ull)(0xFFFFFFFFu - (unsigned)n);
  labels[(size_t)b * NLOC + n] = bi + 1;
  float* bx = boxes + ((size_t)b * NLOC + n) * 4;
  bx[0] = x - r0; bx[1] = y - r1; bx[2] = x + r2; bx[3] = y + r3;
}

// ---------------------------------------------------------------- kernel 2 --
// Bitonic sort of one 2048 chunk in LDS (descending); emit top-1024.
__global__ __launch_bounds__(512) void chunk_sort_kernel(const ull* __restrict__ keys,
                                                         ull* __restrict__ runs) {
  __shared__ ull s[CHUNK];
  int b = blockIdx.x / NCHUNK, c = blockIdx.x % NCHUNK;
  const ull* src = keys + (size_t)b * NPAD + (size_t)c * CHUNK;
  for (int i = threadIdx.x; i < CHUNK; i += 512) s[i] = src[i];
  __syncthreads();
  for (int k = 2; k <= CHUNK; k <<= 1) {
    for (int j = k >> 1; j > 0; j >>= 1) {
      for (int t = threadIdx.x; t < CHUNK / 2; t += 512) {
        int i = ((t & ~(j - 1)) << 1) | (t & (j - 1));
        int ixj = i | j;
        bool desc = (i & k) == 0;
        ull a = s[i], bb = s[ixj];
        bool sw = desc ? (a < bb) : (a > bb);
        if (sw) { s[i] = bb; s[ixj] = a; }
      }
      __syncthreads();
    }
  }
  ull* dst = runs + ((size_t)b * NCHUNK + c) * TOPKP;
  for (int i = threadIdx.x; i < TOPKP; i += 512) dst[i] = s[i];
}

// ---------------------------------------------------------------- kernel 3 --
// One tree-merge level: block (b,p) merges src runs (2p,2p+1) -> dst run p,
// keeping only the top-1024 (first bitonic-merge pass + descending clean of
// the top half). Carry block copies the odd run through. Ping-pong buffers.
__global__ __launch_bounds__(512) void merge_level_kernel(const ull* __restrict__ src,
    ull* __restrict__ dst, int npairs, int carry, int srcRPI, int dstRPI) {
  int per = npairs + carry;
  int b = blockIdx.x / per, p = blockIdx.x % per;
  const ull* sb = src + (size_t)b * srcRPI * TOPKP;
  ull* db = dst + (size_t)b * dstRPI * TOPKP;
  int tid = threadIdx.x;
  if (p >= npairs) {   // carry: copy last odd run through
    for (int i = tid; i < TOPKP; i += 512)
      db[(size_t)p * TOPKP + i] = sb[(size_t)(2 * npairs) * TOPKP + i];
    return;
  }
  __shared__ ull m[TOPKP];
  const ull* A = sb + (size_t)(2 * p) * TOPKP;
  const ull* B = sb + (size_t)(2 * p + 1) * TOPKP;
  // pass j=1024 of the 2048 bitonic merge: top half = max(A[i], B[1023-i])
  for (int i = tid; i < TOPKP; i += 512) {
    ull a = A[i], c = B[TOPKP - 1 - i];
    m[i] = a > c ? a : c;
  }
  __syncthreads();
  // descending bitonic clean of the (bitonic) top half
  for (int j = TOPKP / 2; j > 0; j >>= 1) {
    for (int t = tid; t < TOPKP / 2; t += 512) {
      int i = ((t & ~(j - 1)) << 1) | (t & (j - 1));
      int ixj = i | j;
      ull a = m[i], c = m[ixj];
      if (a < c) { m[i] = c; m[ixj] = a; }
    }
    __syncthreads();
  }
  for (int i = tid; i < TOPKP; i += 512) db[(size_t)p * TOPKP + i] = m[i];
}

// ---------------------------------------------------------------- kernel 4 --
// Decode keys, gather label/box, write output boxes, coord_max reduction
// (exact: max is order-independent), class-offset boxes, valid-bit words.
__global__ __launch_bounds__(256) void gather_kernel(const ull* __restrict__ topkeys,
    const int* __restrict__ labels, const float* __restrict__ boxes,
    float* __restrict__ topS, int* __restrict__ topL, float* __restrict__ topOB,
    ull* __restrict__ validWords, float* __restrict__ outBoxes) {
  __shared__ float red[256];
  __shared__ float s_cmax;
  int b = blockIdx.x, tid = threadIdx.x;
  float lmax = 0.f;   // reference maxes over where(valid, bx, 0) -> zeros included
  for (int k = tid; k < TOPKP; k += 256) {
    ull key = topkeys[(size_t)b * TOPKP + k];
    float sc = 0.f; int lb = 0;
    float b0 = 0.f, b1 = 0.f, b2 = 0.f, b3 = 0.f;
    bool inR = (k < TOPK);
    if (inR) {
      sc = __uint_as_float((unsigned)(key >> 32));
      unsigned n = 0xFFFFFFFFu - (unsigned)(key & 0xFFFFFFFFull);
      lb = labels[(size_t)b * NLOC + n];
      const float* bp = boxes + ((size_t)b * NLOC + n) * 4;
      b0 = bp[0]; b1 = bp[1]; b2 = bp[2]; b3 = bp[3];
      float* ob = outBoxes + ((size_t)b * TOPK + k) * 4;
      ob[0] = b0; ob[1] = b1; ob[2] = b2; ob[3] = b3;   // boxes output: all 1000
    }
    topS[(size_t)b * TOPKP + k] = sc;
    topL[(size_t)b * TOPKP + k] = lb;
    float* tb = topOB + ((size_t)b * TOPKP + k) * 4;
    tb[0] = b0; tb[1] = b1; tb[2] = b2; tb[3] = b3;
    bool valid = inR && (sc > SCORE_THR);
    if (valid) lmax = fmaxf(lmax, fmaxf(fmaxf(b0, b1), fmaxf(b2, b3)));
    ull vb = __ballot(valid ? 1 : 0);
    if ((tid & 63) == 0) validWords[b * 16 + (k >> 6)] = vb;
  }
  red[tid] = lmax;
  __syncthreads();
  for (int sft = 128; sft > 0; sft >>= 1) {
    if (tid < sft) red[tid] = fmaxf(red[tid], red[tid + sft]);
    __syncthreads();
  }
  if (tid == 0) s_cmax = red[0];
  __syncthreads();
  float offb = s_cmax + 1.0f;
  for (int k = tid; k < TOPKP; k += 256) {
    float off = (float)topL[(size_t)b * TOPKP + k] * offb;   // class-offset trick
    float* tb = topOB + ((size_t)b * TOPKP + k) * 4;
    tb[0] += off; tb[1] += off; tb[2] += off; tb[3] += off;
  }
}

// ---------------------------------------------------------------- kernel 5 --
// Suppression bitmask: block (b,i), thread j: bit = (j>i) & (iou(i,j) > thr).
// 16 uint64 words per row via per-wave ballot. Row stride = 16 words; rows
// stored at (b*TOPKP + i). FP op order mirrors reference.
__global__ __launch_bounds__(1024) void sup_kernel(const float* __restrict__ topOB,
                                                   ull* __restrict__ sup) {
  int bid = blockIdx.x;
  int b = bid / TOPK, i = bid - b * TOPK;
  int j = threadIdx.x;
  const float4* OB = (const float4*)topOB + (size_t)b * TOPKP;
  float4 A = OB[i];
  float aw = fmaxf(A.z - A.x, 0.f), ah = fmaxf(A.w - A.y, 0.f);
  float areaA = aw * ah;
  bool bit = false;
  if (j > i && j < TOPK) {
    float4 Bx = OB[j];
    float bw = fmaxf(Bx.z - Bx.x, 0.f), bh = fmaxf(Bx.w - Bx.y, 0.f);
    float areaB = bw * bh;
    float ix1 = fmaxf(A.x, Bx.x), iy1 = fmaxf(A.y, Bx.y);
    float ix2 = fminf(A.z, Bx.z), iy2 = fminf(A.w, Bx.w);
    float inter = fmaxf(ix2 - ix1, 0.f) * fmaxf(iy2 - iy1, 0.f);
    float uni = areaA + areaB - inter;
    float iou = inter / fmaxf(uni, 1e-9f);
    bit = iou > IOU_THR;
  }
  ull m = __ballot(bit ? 1 : 0);
  if ((j & 63) == 0) sup[((size_t)b * TOPKP + i) * 16 + (j >> 6)] = m;
}

// ---------------------------------------------------------------- kernel 6 --
// Span-based greedy scan, 1 wave per image. Lanes 0..15 own removed word lane.
// Per 64-candidate span w: load the WHOLE 64x16-word sub-block lane-parallel
// into 16 named regs (lane holds word lane&15 of rows (lane>>4)+4t) -- one
// coalesced burst + one vmcnt wait per span. The serial chain gets diag value
// d[k] via __shfl(v_t, (g<<4)|w) -- shfls are chain-independent (pipelined).
// Phase B is register-only: OR v_t under the kept mask, fold 4 lane-groups
// with 2 shfl_xor. No per-step loads, no uniform (scalar) loads -- R6 showed
// uniform diag loads scalarize to s_load whose out-of-order returns force
// lgkmcnt(0) per step = full memory latency per chain step (343 us).
__global__ __launch_bounds__(64) void nms_scan_kernel(const ull* __restrict__ sup,
    const ull* __restrict__ validWords, const float* __restrict__ topS,
    const int* __restrict__ topL, float* __restrict__ out) {
  int b = blockIdx.x, lane = threadIdx.x;
  const ull* S = sup + (size_t)b * TOPKP * 16;
  int lg = lane >> 4;    // lane group -> row offset mod 4
  int wd = lane & 15;    // word index owned by this lane
  ull rm = 0xFFFFFFFFFFFFFFFFull;
  if (lane < 16) rm = ~validWords[b * 16 + lane];   // removed = ~valid initially

  for (int w = 0; w < 16; ++w) {
    // ---- load span sub-block: v##t = sup_row(w*64 + lg + 4t)[wd] ----
    const ull* Bp = S + ((size_t)w * 64 + lg) * 16 + wd;
    ull v0, v1, v2, v3, v4, v5, v6, v7, v8, v9, v10, v11, v12, v13, v14, v15;
#define LDV(t) v##t = Bp[(size_t)(4 * (t)) * 16];
    LDV(0) LDV(1) LDV(2) LDV(3) LDV(4) LDV(5) LDV(6) LDV(7)
    LDV(8) LDV(9) LDV(10) LDV(11) LDV(12) LDV(13) LDV(14) LDV(15)
#undef LDV
    // ---- phase A: serial 64-step scan on broadcast word w ----
    ull rmw = __shfl(rm, w);
    ull km = 0;
    // step k = 4t+g: diag value lives in v##t on lane (g<<4)|w.
    // take = (bit k of rmw clear) ? ~0 : 0  (branchless)
#define CH(t, g) { ull dv = __shfl(v##t, ((g) << 4) + w);                      \
    int k = 4 * (t) + (g); ull tk = ((rmw >> k) & 1ull) - 1ull;                \
    rmw |= dv & tk; km |= (1ull << k) & tk; }
#define CH4(t) CH(t, 0) CH(t, 1) CH(t, 2) CH(t, 3)
    CH4(0) CH4(1) CH4(2) CH4(3) CH4(4) CH4(5) CH4(6) CH4(7)
    CH4(8) CH4(9) CH4(10) CH4(11) CH4(12) CH4(13) CH4(14) CH4(15)
#undef CH4
#undef CH
    // ---- phase B: OR kept rows' words into owners, register-only ----
    ull accB = 0;
#define PB(t) { ull bit = (km >> (4 * (t) + lg)) & 1ull;                       \
    accB |= v##t & (0ull - bit); }
    PB(0) PB(1) PB(2) PB(3) PB(4) PB(5) PB(6) PB(7)
    PB(8) PB(9) PB(10) PB(11) PB(12) PB(13) PB(14) PB(15)
#undef PB
    accB |= __shfl_xor(accB, 16);
    accB |= __shfl_xor(accB, 32);   // fold 4 lane groups -> every lane of wd
    rm |= accB;                     // lanes >=16: rm stays all-ones (harmless)
  }

  ull keep_na = ~rm;   // lanes 0..15: keep word lane (~rm subset of valid)
  const float* tS = topS + (size_t)b * TOPKP;
  const int*   tL = topL + (size_t)b * TOPKP;
  float* outS = out;                          // [16,1000]
  float* outL = out + BATCH * TOPK;           // [16,1000] labels as float
  float* outK = out + BATCH * TOPK * 6;       // after boxes block
  for (int t = 0; t < 16; ++t) {
    int j = t * 64 + lane;
    ull kw = __shfl(keep_na, t);
    if (j < TOPK) {
      bool kp = (kw >> lane) & 1ull;
      outS[(size_t)b * TOPK + j] = kp ? tS[j] : 0.f;
      outL[(size_t)b * TOPK + j] = kp ? (float)tL[j] : 0.f;
      outK[(size_t)b * TOPK + j] = kp ? 1.f : 0.f;
    }
  }
}

// -------------------------------------------------------------------- host --
extern "C" void kernel_launch(void* const* d_in, const int* in_sizes, int n_in,
                              void* d_out, int out_size, void* d_ws, size_t ws_size,
                              hipStream_t stream) {
  Ptrs p;
  for (int l = 0; l < 5; ++l) {
    p.cls[l] = (const float*)d_in[l];
    p.reg[l] = (const float*)d_in[5 + l];
    p.ctr[l] = (const float*)d_in[10 + l];
  }
  char* ws = (char*)d_ws;
  size_t o = 0;
  auto alloc = [&](size_t bytes) -> void* {
    void* r = ws + o; o += (bytes + 255) & ~(size_t)255; return r;
  };
  ull*   keys       = (ull*)  alloc((size_t)BATCH * NPAD * 8);
  int*   labels     = (int*)  alloc((size_t)BATCH * NLOC * 4);
  float* boxes      = (float*)alloc((size_t)BATCH * NLOC * 16);
  ull*   runs       = (ull*)  alloc((size_t)BATCH * NCHUNK * TOPKP * 8);
  ull*   runs2      = (ull*)  alloc((size_t)BATCH * NCHUNK * TOPKP * 8);
  ull*   topkeys    = (ull*)  alloc((size_t)BATCH * TOPKP * 8);
  float* topS       = (float*)alloc((size_t)BATCH * TOPKP * 4);
  int*   topL       = (int*)  alloc((size_t)BATCH * TOPKP * 4);
  float* topOB      = (float*)alloc((size_t)BATCH * TOPKP * 16);
  ull*   validWords = (ull*)  alloc((size_t)BATCH * 16 * 8);
  ull*   sup        = (ull*)  alloc((size_t)BATCH * TOPKP * 16 * 8);

  float* out = (float*)d_out;
  float* outBoxes = out + 2 * BATCH * TOPK;   // offset 32000

  hipLaunchKernelGGL(score_kernel, dim3((BATCH * NPAD + 255) / 256), dim3(256), 0, stream,
                     p, keys, labels, boxes);
  hipLaunchKernelGGL(chunk_sort_kernel, dim3(BATCH * NCHUNK), dim3(512), 0, stream,
                     keys, runs);
  // tree merge: 9 -> 5 -> 3 -> 2 -> 1 (ping-pong runs/runs2)
  hipLaunchKernelGGL(merge_level_kernel, dim3(BATCH * 5), dim3(512), 0, stream,
                     runs, runs2, 4, 1, NCHUNK, NCHUNK);
  hipLaunchKernelGGL(merge_level_kernel, dim3(BATCH * 3), dim3(512), 0, stream,
                     runs2, runs, 2, 1, NCHUNK, NCHUNK);
  hipLaunchKernelGGL(merge_level_kernel, dim3(BATCH * 2), dim3(512), 0, stream,
                     runs, runs2, 1, 1, NCHUNK, NCHUNK);
  hipLaunchKernelGGL(merge_level_kernel, dim3(BATCH * 1), dim3(512), 0, stream,
                     runs2, topkeys, 1, 0, NCHUNK, 1);
  hipLaunchKernelGGL(gather_kernel, dim3(BATCH), dim3(256), 0, stream,
                     topkeys, labels, boxes, topS, topL, topOB, validWords, outBoxes);
  hipLaunchKernelGGL(sup_kernel, dim3(BATCH * TOPK), dim3(1024), 0, stream,
                     topOB, sup);
  hipLaunchKernelGGL(nms_scan_kernel, dim3(BATCH), dim3(64), 0, stream,
                     sup, validWords, topS, topL, out);
}

// Round 8
// 253.844 us; speedup vs baseline: 2.2729x; 1.0069x over previous
//
#include <hip/hip_runtime.h>
#include <cstdint>

// FCOS detection post-process for MI355X.
// Pipeline: score/box decode -> per-image exact top-1000 (bitonic chunk sort +
// tree merge) -> suppression bitmask -> span-based greedy NMS scan -> outputs.

typedef unsigned long long ull;

#define BATCH 16
#define NLOC 17064      // total FPN locations per image
#define NPAD 18432      // padded to 9 * 2048
#define NCHUNK 9
#define CHUNK 2048
#define TOPK 1000
#define TOPKP 1024
#define NCLS 80
#define SCORE_THR 0.05f
#define IOU_THR 0.6f

struct Ptrs { const float* cls[5]; const float* reg[5]; const float* ctr[5]; };

// ---------------------------------------------------------------- kernel 1 --
// One thread per (image, location): argmax over 80 class logits (sigmoid is
// monotonic), score = sqrt(sig(cls_max)*sig(ctr)), box decode, pack sort key.
// Key = (score_bits << 32) | (0xFFFFFFFF - n): descending sort == lax.top_k
// order (ties -> smaller index first). Padding locations get key 0.
__global__ __launch_bounds__(256) void score_kernel(Ptrs p, ull* __restrict__ keys,
                                                    int* __restrict__ labels,
                                                    float* __restrict__ boxes) {
  int idx = blockIdx.x * 256 + threadIdx.x;
  if (idx >= BATCH * NPAD) return;
  int b = idx / NPAD, n = idx - b * NPAD;
  if (n >= NLOC) { keys[idx] = 0ull; return; }

  int lvl, off, lw, st, H;
  if (n < 12800)      { lvl=0; off=0;     lw=7; st=8;   H=100; }
  else if (n < 16000) { lvl=1; off=12800; lw=6; st=16;  H=50;  }
  else if (n < 16800) { lvl=2; off=16000; lw=5; st=32;  H=25;  }
  else if (n < 17008) { lvl=3; off=16800; lw=4; st=64;  H=13;  }
  else                { lvl=4; off=17008; lw=3; st=128; H=7;   }
  int hw = n - off;
  int w = hw & ((1 << lw) - 1), h = hw >> lw;
  int HW = H << lw;
  float fs = (float)st, half = fs * 0.5f;
  float x = (float)w * fs + half, y = (float)h * fs + half;

  // coalesced across threads (consecutive hw) for each class c
  const float* cb = p.cls[lvl] + (size_t)b * NCLS * HW + hw;
  float best = cb[0]; int bi = 0;
  for (int c = 1; c < NCLS; ++c) {
    float v = cb[(size_t)c * HW];
    if (v > best) { best = v; bi = c; }   // strict > keeps first max (jnp.argmax)
  }
  const float* rb = p.reg[lvl] + (size_t)b * 4 * HW + hw;
  float r0 = rb[0], r1 = rb[HW], r2 = rb[2 * (size_t)HW], r3 = rb[3 * (size_t)HW];
  float ct = p.ctr[lvl][(size_t)b * HW + hw];

  float pcls = 1.f / (1.f + expf(-best));
  float pctr = 1.f / (1.f + expf(-ct));
  float score = sqrtf(pcls * pctr);   // (0,1), always positive -> monotonic bits

  keys[idx] = ((ull)__float_as_uint(score) << 32) | (ull)(0xFFFFFFFFu - (unsigned)n);
  labels[(size_t)b * NLOC + n] = bi + 1;
  float* bx = boxes + ((size_t)b * NLOC + n) * 4;
  bx[0] = x - r0; bx[1] = y - r1; bx[2] = x + r2; bx[3] = y + r3;
}

// ---------------------------------------------------------------- kernel 2 --
// Bitonic sort of one 2048 chunk in LDS (descending); emit top-1024.
__global__ __launch_bounds__(512) void chunk_sort_kernel(const ull* __restrict__ keys,
                                                         ull* __restrict__ runs) {
  __shared__ ull s[CHUNK];
  int b = blockIdx.x / NCHUNK, c = blockIdx.x % NCHUNK;
  const ull* src = keys + (size_t)b * NPAD + (size_t)c * CHUNK;
  for (int i = threadIdx.x; i < CHUNK; i += 512) s[i] = src[i];
  __syncthreads();
  for (int k = 2; k <= CHUNK; k <<= 1) {
    for (int j = k >> 1; j > 0; j >>= 1) {
      for (int t = threadIdx.x; t < CHUNK / 2; t += 512) {
        int i = ((t & ~(j - 1)) << 1) | (t & (j - 1));
        int ixj = i | j;
        bool desc = (i & k) == 0;
        ull a = s[i], bb = s[ixj];
        bool sw = desc ? (a < bb) : (a > bb);
        if (sw) { s[i] = bb; s[ixj] = a; }
      }
      __syncthreads();
    }
  }
  ull* dst = runs + ((size_t)b * NCHUNK + c) * TOPKP;
  for (int i = threadIdx.x; i < TOPKP; i += 512) dst[i] = s[i];
}

// ---------------------------------------------------------------- kernel 3 --
// One tree-merge level: block (b,p) merges src runs (2p,2p+1) -> dst run p,
// keeping only the top-1024 (first bitonic-merge pass + descending clean of
// the top half). Carry block copies the odd run through. Ping-pong buffers.
__global__ __launch_bounds__(512) void merge_level_kernel(const ull* __restrict__ src,
    ull* __restrict__ dst, int npairs, int carry, int srcRPI, int dstRPI) {
  int per = npairs + carry;
  int b = blockIdx.x / per, p = blockIdx.x % per;
  const ull* sb = src + (size_t)b * srcRPI * TOPKP;
  ull* db = dst + (size_t)b * dstRPI * TOPKP;
  int tid = threadIdx.x;
  if (p >= npairs) {   // carry: copy last odd run through
    for (int i = tid; i < TOPKP; i += 512)
      db[(size_t)p * TOPKP + i] = sb[(size_t)(2 * npairs) * TOPKP + i];
    return;
  }
  __shared__ ull m[TOPKP];
  const ull* A = sb + (size_t)(2 * p) * TOPKP;
  const ull* B = sb + (size_t)(2 * p + 1) * TOPKP;
  // pass j=1024 of the 2048 bitonic merge: top half = max(A[i], B[1023-i])
  for (int i = tid; i < TOPKP; i += 512) {
    ull a = A[i], c = B[TOPKP - 1 - i];
    m[i] = a > c ? a : c;
  }
  __syncthreads();
  // descending bitonic clean of the (bitonic) top half
  for (int j = TOPKP / 2; j > 0; j >>= 1) {
    for (int t = tid; t < TOPKP / 2; t += 512) {
      int i = ((t & ~(j - 1)) << 1) | (t & (j - 1));
      int ixj = i | j;
      ull a = m[i], c = m[ixj];
      if (a < c) { m[i] = c; m[ixj] = a; }
    }
    __syncthreads();
  }
  for (int i = tid; i < TOPKP; i += 512) db[(size_t)p * TOPKP + i] = m[i];
}

// ---------------------------------------------------------------- kernel 4 --
// Decode keys, gather label/box, write output boxes, coord_max reduction
// (exact: max is order-independent), class-offset boxes, valid-bit words.
__global__ __launch_bounds__(256) void gather_kernel(const ull* __restrict__ topkeys,
    const int* __restrict__ labels, const float* __restrict__ boxes,
    float* __restrict__ topS, int* __restrict__ topL, float* __restrict__ topOB,
    ull* __restrict__ validWords, float* __restrict__ outBoxes) {
  __shared__ float red[256];
  __shared__ float s_cmax;
  int b = blockIdx.x, tid = threadIdx.x;
  float lmax = 0.f;   // reference maxes over where(valid, bx, 0) -> zeros included
  for (int k = tid; k < TOPKP; k += 256) {
    ull key = topkeys[(size_t)b * TOPKP + k];
    float sc = 0.f; int lb = 0;
    float b0 = 0.f, b1 = 0.f, b2 = 0.f, b3 = 0.f;
    bool inR = (k < TOPK);
    if (inR) {
      sc = __uint_as_float((unsigned)(key >> 32));
      unsigned n = 0xFFFFFFFFu - (unsigned)(key & 0xFFFFFFFFull);
      lb = labels[(size_t)b * NLOC + n];
      const float* bp = boxes + ((size_t)b * NLOC + n) * 4;
      b0 = bp[0]; b1 = bp[1]; b2 = bp[2]; b3 = bp[3];
      float* ob = outBoxes + ((size_t)b * TOPK + k) * 4;
      ob[0] = b0; ob[1] = b1; ob[2] = b2; ob[3] = b3;   // boxes output: all 1000
    }
    topS[(size_t)b * TOPKP + k] = sc;
    topL[(size_t)b * TOPKP + k] = lb;
    float* tb = topOB + ((size_t)b * TOPKP + k) * 4;
    tb[0] = b0; tb[1] = b1; tb[2] = b2; tb[3] = b3;
    bool valid = inR && (sc > SCORE_THR);
    if (valid) lmax = fmaxf(lmax, fmaxf(fmaxf(b0, b1), fmaxf(b2, b3)));
    ull vb = __ballot(valid ? 1 : 0);
    if ((tid & 63) == 0) validWords[b * 16 + (k >> 6)] = vb;
  }
  red[tid] = lmax;
  __syncthreads();
  for (int sft = 128; sft > 0; sft >>= 1) {
    if (tid < sft) red[tid] = fmaxf(red[tid], red[tid + sft]);
    __syncthreads();
  }
  if (tid == 0) s_cmax = red[0];
  __syncthreads();
  float offb = s_cmax + 1.0f;
  for (int k = tid; k < TOPKP; k += 256) {
    float off = (float)topL[(size_t)b * TOPKP + k] * offb;   // class-offset trick
    float* tb = topOB + ((size_t)b * TOPKP + k) * 4;
    tb[0] += off; tb[1] += off; tb[2] += off; tb[3] += off;
  }
}

// ---------------------------------------------------------------- kernel 5 --
// Suppression bitmask: block (b,i), thread j: bit = (j>i) & (iou(i,j) > thr).
// 16 uint64 words per row via per-wave ballot. Row stride = 16 words; rows
// stored at (b*TOPKP + i). FP op order mirrors reference.
__global__ __launch_bounds__(1024) void sup_kernel(const float* __restrict__ topOB,
                                                   ull* __restrict__ sup) {
  int bid = blockIdx.x;
  int b = bid / TOPK, i = bid - b * TOPK;
  int j = threadIdx.x;
  const float4* OB = (const float4*)topOB + (size_t)b * TOPKP;
  float4 A = OB[i];
  float aw = fmaxf(A.z - A.x, 0.f), ah = fmaxf(A.w - A.y, 0.f);
  float areaA = aw * ah;
  bool bit = false;
  if (j > i && j < TOPK) {
    float4 Bx = OB[j];
    float bw = fmaxf(Bx.z - Bx.x, 0.f), bh = fmaxf(Bx.w - Bx.y, 0.f);
    float areaB = bw * bh;
    float ix1 = fmaxf(A.x, Bx.x), iy1 = fmaxf(A.y, Bx.y);
    float ix2 = fminf(A.z, Bx.z), iy2 = fminf(A.w, Bx.w);
    float inter = fmaxf(ix2 - ix1, 0.f) * fmaxf(iy2 - iy1, 0.f);
    float uni = areaA + areaB - inter;
    float iou = inter / fmaxf(uni, 1e-9f);
    bit = iou > IOU_THR;
  }
  ull m = __ballot(bit ? 1 : 0);
  if ((j & 63) == 0) sup[((size_t)b * TOPKP + i) * 16 + (j >> 6)] = m;
}

// ---------------------------------------------------------------- kernel 6 --
// Span-based greedy scan, 1 wave per image. Lanes 0..15 own removed word lane.
// Per span w: 64x16-word sub-block held lane-parallel in a reg bank (lane =
// word lane&15 of rows (lane>>4)+4t). Span loads are DOUBLE-BUFFERED (bank
// va/vb): span w+1's 16 loads issue before span w's chain -> HBM latency
// hides under compute (counted vmcnt). The serial chain consumes broadcast
// diag values via shfl, PREFETCHED 16-at-a-time into q0..q15 (DS returns
// in-order -> only the first consume waits; R7 showed per-step shfl+wait
// cost ~40cyc x 1024 steps = the 45us). Phase B register-only + 2 shfl_xor.
__global__ __launch_bounds__(64) void nms_scan_kernel(const ull* __restrict__ sup,
    const ull* __restrict__ validWords, const float* __restrict__ topS,
    const int* __restrict__ topL, float* __restrict__ out) {
  int b = blockIdx.x, lane = threadIdx.x;
  const ull* S = sup + (size_t)b * TOPKP * 16;
  int lg = lane >> 4;    // lane group -> row offset mod 4
  int wd = lane & 15;    // word index owned by this lane
  ull rm = 0xFFFFFFFFFFFFFFFFull;
  if (lane < 16) rm = ~validWords[b * 16 + lane];   // removed = ~valid initially

  ull va0,va1,va2,va3,va4,va5,va6,va7,va8,va9,va10,va11,va12,va13,va14,va15;
  ull vb0,vb1,vb2,vb3,vb4,vb5,vb6,vb7,vb8,vb9,vb10,vb11,vb12,vb13,vb14,vb15;
  ull q0,q1,q2,q3,q4,q5,q6,q7,q8,q9,q10,q11,q12,q13,q14,q15;

  // load bank PFX with span W's sub-block: PFX#t = row(W*64 + lg + 4t)[wd]
#define LOADS(PFX, W) { const ull* Bp = S + ((size_t)(W) * 64 + lg) * 16 + wd; \
    PFX##0 = Bp[0];    PFX##1 = Bp[64];   PFX##2 = Bp[128];  PFX##3 = Bp[192]; \
    PFX##4 = Bp[256];  PFX##5 = Bp[320];  PFX##6 = Bp[384];  PFX##7 = Bp[448]; \
    PFX##8 = Bp[512];  PFX##9 = Bp[576];  PFX##10 = Bp[640]; PFX##11 = Bp[704];\
    PFX##12 = Bp[768]; PFX##13 = Bp[832]; PFX##14 = Bp[896]; PFX##15 = Bp[960];}
  // broadcast diag value for step k=4T+G: lives in PFX#T on lane (G<<4)+w
#define SH(PFX, T, G) __shfl(PFX##T, ((G) << 4) + w_)
#define QBLK(PFX, T0, T1, T2, T3) \
    q0 = SH(PFX,T0,0); q1 = SH(PFX,T0,1); q2 = SH(PFX,T0,2); q3 = SH(PFX,T0,3);\
    q4 = SH(PFX,T1,0); q5 = SH(PFX,T1,1); q6 = SH(PFX,T1,2); q7 = SH(PFX,T1,3);\
    q8 = SH(PFX,T2,0); q9 = SH(PFX,T2,1); q10= SH(PFX,T2,2); q11= SH(PFX,T2,3);\
    q12= SH(PFX,T3,0); q13= SH(PFX,T3,1); q14= SH(PFX,T3,2); q15= SH(PFX,T3,3);
  // one chain step (branchless): take = bit K of rmw clear
#define CQ(QI, K) { ull tk = ((rmw >> (K)) & 1ull) - 1ull;                     \
    rmw |= q##QI & tk; km |= (1ull << (K)) & tk; }
#define CQ16(B) CQ(0,(B)+0) CQ(1,(B)+1) CQ(2,(B)+2) CQ(3,(B)+3) CQ(4,(B)+4)    \
    CQ(5,(B)+5) CQ(6,(B)+6) CQ(7,(B)+7) CQ(8,(B)+8) CQ(9,(B)+9) CQ(10,(B)+10)  \
    CQ(11,(B)+11) CQ(12,(B)+12) CQ(13,(B)+13) CQ(14,(B)+14) CQ(15,(B)+15)
#define PB(PFX, T) { ull bit = (km >> (4 * (T) + lg)) & 1ull;                  \
    accB |= PFX##T & (0ull - bit); }
#define SPAN_BODY(PFX, W) { int w_ = (W);                                      \
    ull rmw = __shfl(rm, w_); ull km = 0;                                      \
    QBLK(PFX, 0, 1, 2, 3)     CQ16(0)                                          \
    QBLK(PFX, 4, 5, 6, 7)     CQ16(16)                                         \
    QBLK(PFX, 8, 9, 10, 11)   CQ16(32)                                         \
    QBLK(PFX, 12, 13, 14, 15) CQ16(48)                                         \
    ull accB = 0;                                                              \
    PB(PFX,0) PB(PFX,1) PB(PFX,2) PB(PFX,3) PB(PFX,4) PB(PFX,5) PB(PFX,6)      \
    PB(PFX,7) PB(PFX,8) PB(PFX,9) PB(PFX,10) PB(PFX,11) PB(PFX,12) PB(PFX,13)  \
    PB(PFX,14) PB(PFX,15)                                                      \
    accB |= __shfl_xor(accB, 16);                                              \
    accB |= __shfl_xor(accB, 32);                                              \
    rm |= accB; }

  LOADS(va, 0)
  for (int w = 0; w < 16; w += 2) {
    int wn1 = (w + 1 < 16) ? w + 1 : 15;
    LOADS(vb, wn1)            // in flight during va's chain
    SPAN_BODY(va, w)
    int wn2 = (w + 2 < 16) ? w + 2 : 15;
    LOADS(va, wn2)            // in flight during vb's chain
    SPAN_BODY(vb, w + 1)
  }
#undef SPAN_BODY
#undef PB
#undef CQ16
#undef CQ
#undef QBLK
#undef SH
#undef LOADS

  ull keep_na = ~rm;   // lanes 0..15: keep word lane (~rm subset of valid)
  const float* tS = topS + (size_t)b * TOPKP;
  const int*   tL = topL + (size_t)b * TOPKP;
  float* outS = out;                          // [16,1000]
  float* outL = out + BATCH * TOPK;           // [16,1000] labels as float
  float* outK = out + BATCH * TOPK * 6;       // after boxes block
  for (int t = 0; t < 16; ++t) {
    int j = t * 64 + lane;
    ull kw = __shfl(keep_na, t);
    if (j < TOPK) {
      bool kp = (kw >> lane) & 1ull;
      outS[(size_t)b * TOPK + j] = kp ? tS[j] : 0.f;
      outL[(size_t)b * TOPK + j] = kp ? (float)tL[j] : 0.f;
      outK[(size_t)b * TOPK + j] = kp ? 1.f : 0.f;
    }
  }
}

// -------------------------------------------------------------------- host --
extern "C" void kernel_launch(void* const* d_in, const int* in_sizes, int n_in,
                              void* d_out, int out_size, void* d_ws, size_t ws_size,
                              hipStream_t stream) {
  Ptrs p;
  for (int l = 0; l < 5; ++l) {
    p.cls[l] = (const float*)d_in[l];
    p.reg[l] = (const float*)d_in[5 + l];
    p.ctr[l] = (const float*)d_in[10 + l];
  }
  char* ws = (char*)d_ws;
  size_t o = 0;
  auto alloc = [&](size_t bytes) -> void* {
    void* r = ws + o; o += (bytes + 255) & ~(size_t)255; return r;
  };
  ull*   keys       = (ull*)  alloc((size_t)BATCH * NPAD * 8);
  int*   labels     = (int*)  alloc((size_t)BATCH * NLOC * 4);
  float* boxes      = (float*)alloc((size_t)BATCH * NLOC * 16);
  ull*   runs       = (ull*)  alloc((size_t)BATCH * NCHUNK * TOPKP * 8);
  ull*   runs2      = (ull*)  alloc((size_t)BATCH * NCHUNK * TOPKP * 8);
  ull*   topkeys    = (ull*)  alloc((size_t)BATCH * TOPKP * 8);
  float* topS       = (float*)alloc((size_t)BATCH * TOPKP * 4);
  int*   topL       = (int*)  alloc((size_t)BATCH * TOPKP * 4);
  float* topOB      = (float*)alloc((size_t)BATCH * TOPKP * 16);
  ull*   validWords = (ull*)  alloc((size_t)BATCH * 16 * 8);
  ull*   sup        = (ull*)  alloc((size_t)BATCH * TOPKP * 16 * 8);

  float* out = (float*)d_out;
  float* outBoxes = out + 2 * BATCH * TOPK;   // offset 32000

  hipLaunchKernelGGL(score_kernel, dim3((BATCH * NPAD + 255) / 256), dim3(256), 0, stream,
                     p, keys, labels, boxes);
  hipLaunchKernelGGL(chunk_sort_kernel, dim3(BATCH * NCHUNK), dim3(512), 0, stream,
                     keys, runs);
  // tree merge: 9 -> 5 -> 3 -> 2 -> 1 (ping-pong runs/runs2)
  hipLaunchKernelGGL(merge_level_kernel, dim3(BATCH * 5), dim3(512), 0, stream,
                     runs, runs2, 4, 1, NCHUNK, NCHUNK);
  hipLaunchKernelGGL(merge_level_kernel, dim3(BATCH * 3), dim3(512), 0, stream,
                     runs2, runs, 2, 1, NCHUNK, NCHUNK);
  hipLaunchKernelGGL(merge_level_kernel, dim3(BATCH * 2), dim3(512), 0, stream,
                     runs, runs2, 1, 1, NCHUNK, NCHUNK);
  hipLaunchKernelGGL(merge_level_kernel, dim3(BATCH * 1), dim3(512), 0, stream,
                     runs2, topkeys, 1, 0, NCHUNK, 1);
  hipLaunchKernelGGL(gather_kernel, dim3(BATCH), dim3(256), 0, stream,
                     topkeys, labels, boxes, topS, topL, topOB, validWords, outBoxes);
  hipLaunchKernelGGL(sup_kernel, dim3(BATCH * TOPK), dim3(1024), 0, stream,
                     topOB, sup);
  hipLaunchKernelGGL(nms_scan_kernel, dim3(BATCH), dim3(64), 0, stream,
                     sup, validWords, topS, topL, out);
}